// Round 2
// baseline (775.088 us; speedup 1.0000x reference)
//
#include <hip/hip_runtime.h>
#include <cstdint>

#define DEVINL __device__ __forceinline__

// ---------------- problem geometry ----------------
constexpr int NB = 8;        // batch
constexpr int NG = 50;       // gts per image
constexpr int KTOT = 120087; // total anchors per image
constexpr int BK = NB * KTOT;

constexpr int L_W[5]   = {100, 50, 25, 13, 7};
constexpr int L_K[5]   = {90000, 22500, 5625, 1521, 441};
constexpr int L_OFF[5] = {0, 90000, 112500, 118125, 119646};
constexpr int L_STR[5] = {8, 16, 32, 64, 128};
constexpr int L_WSB[5] = {0, 720000, 900000, 945000, 957168}; // L_OFF * NB

// base anchor tables (float64, matching numpy bit-for-bit)
constexpr double HR_T[3] = {0.7071067811865476, 1.0, 1.4142135623730951}; // sqrt(ratios)
constexpr double WR_T[3] = {1.0 / HR_T[0], 1.0, 1.0 / HR_T[2]};          // 1/sqrt(ratios)
constexpr double SC_T[3] = {4.0, 5.039684199579493, 6.3496042078727974}; // 4*2^(i/3)

// cls tensor element offsets per level (B*72*HW), cumulative
constexpr int C_OFF[6] = {0, 5760000, 7200000, 7560000, 7657344, 7685568};
// reg tensor element offsets per level (B*36*HW), cumulative
constexpr int R_OFF[6] = {0, 2880000, 3600000, 3780000, 3828672, 3842784};
constexpr int TOTAL_E = C_OFF[5] + R_OFF[5]; // 11,528,352

// ---------------- device-global scratch (avoids any ws_size assumption) ----
__device__ double g_acc[2];
__device__ unsigned g_ns;
__device__ unsigned g_gtmax[NB * NG];
__device__ int8_t g_lab[BK];
__device__ int8_t g_lw[BK];
__device__ int8_t g_pos[BK];
__device__ int8_t g_mg[BK];

// ---------------- helpers ----------------
// monotonic float -> unsigned mapping (order- and equality-preserving)
DEVINL unsigned encf(float f) {
  unsigned u = __float_as_uint(f);
  return (u & 0x80000000u) ? ~u : (u | 0x80000000u);
}
// enc(+0.0f) == 0x80000000u; iou > 0  <=>  enc(iou) > 0x80000000u

DEVINL int lvl_of(int k) {
  return (k < 90000) ? 0 : (k < 112500) ? 1 : (k < 118125) ? 2 : (k < 119646) ? 3 : 4;
}

DEVINL void anchor_box(int l, int r, float& ax0, float& ay0, float& ax1, float& ay1) {
  int loc = r / 9;
  int a = r - loc * 9;
  int W = L_W[l];
  int y = loc / W;
  int x = loc - y * W;
  int st = L_STR[l];
  int ridx = a / 3;
  int sidx = a - ridx * 3;
  double wsz = WR_T[ridx] * SC_T[sidx] * (double)st;
  double hsz = HR_T[ridx] * SC_T[sidx] * (double)st;
  double cx = (double)(x * st);
  double cy = (double)(y * st);
  ax0 = (float)(cx - wsz * 0.5);
  ay0 = (float)(cy - hsz * 0.5);
  ax1 = (float)(cx + wsz * 0.5);
  ay1 = (float)(cy + hsz * 0.5);
}

// single IoU in f32 — the ONLY place IoU is computed (pass A/B bit-identical)
DEVINL float iou_one(float ax0, float ay0, float ax1, float ay1, float areaA,
                     float bx0, float by0, float bx1, float by1) {
  float areaB = (bx1 - bx0) * (by1 - by0);
  float ltx = fmaxf(ax0, bx0);
  float lty = fmaxf(ay0, by0);
  float rbx = fminf(ax1, bx1);
  float rby = fminf(ay1, by1);
  float wx = fmaxf(rbx - ltx, 0.0f);
  float wy = fmaxf(rby - lty, 0.0f);
  float inter = wx * wy;
  return inter / (areaA + areaB - inter);
}

// ---------------- kernel 0: init scratch scalars ----------------
__global__ __launch_bounds__(512) void k_init() {
  int t = threadIdx.x;
  if (t < NB * NG) g_gtmax[t] = 0u; // 0 < enc(-1.0f), valid floor
  if (t == NB * NG) {
    g_acc[0] = 0.0;
    g_acc[1] = 0.0;
    g_ns = 0u;
  }
}

// ---------------- kernel 1: per-(b,g) max IoU over anchors (pass A) ----------------
constexpr int AP = 8; // anchors per thread
__global__ __launch_bounds__(256) void k_gtmax(const float* __restrict__ tb) {
  const int b = blockIdx.y;
  __shared__ float s_box[NG][4];
  int tid = threadIdx.x;
  if (tid < NG) {
    float4 v = reinterpret_cast<const float4*>(tb)[b * NG + tid];
    s_box[tid][0] = v.x; s_box[tid][1] = v.y; s_box[tid][2] = v.z; s_box[tid][3] = v.w;
  }
  __syncthreads();

  unsigned gmax[NG];
#pragma unroll
  for (int g = 0; g < NG; ++g) gmax[g] = 0u;

  int base = blockIdx.x * (256 * AP);
  for (int j = 0; j < AP; ++j) {
    int k = base + j * 256 + tid;
    if (k < KTOT) {
      int l = lvl_of(k);
      int r = k - L_OFF[l];
      float ax0, ay0, ax1, ay1;
      anchor_box(l, r, ax0, ay0, ax1, ay1);
      bool inside = (ax0 >= 0.0f) & (ay0 >= 0.0f) & (ax1 <= 800.0f) & (ay1 <= 800.0f);
      float areaA = (ax1 - ax0) * (ay1 - ay0);
      for (int g = 0; g < NG; ++g) {
        float iou = inside ? iou_one(ax0, ay0, ax1, ay1, areaA,
                                     s_box[g][0], s_box[g][1], s_box[g][2], s_box[g][3])
                           : -1.0f;
        unsigned e = encf(iou);
        gmax[g] = gmax[g] > e ? gmax[g] : e;
      }
    }
  }
  // wave-reduce each g, one global atomic per wave
  for (int g = 0; g < NG; ++g) {
    unsigned v = gmax[g];
    for (int off = 32; off; off >>= 1) {
      unsigned o = (unsigned)__shfl_down((int)v, off);
      v = v > o ? v : o;
    }
    if ((tid & 63) == 0) atomicMax(&g_gtmax[b * NG + g], v);
  }
}

// ---------------- kernel 2: assignment (pass B) ----------------
__global__ __launch_bounds__(256) void k_assign(const float* __restrict__ tb,
                                                const int* __restrict__ tcls) {
  const int b = blockIdx.y;
  __shared__ float s_box[NG][4];
  __shared__ unsigned s_gmax[NG];
  __shared__ int s_cls[NG];
  __shared__ unsigned s_cnt;
  int tid = threadIdx.x;
  if (tid == 0) s_cnt = 0u;
  if (tid < NG) {
    float4 v = reinterpret_cast<const float4*>(tb)[b * NG + tid];
    s_box[tid][0] = v.x; s_box[tid][1] = v.y; s_box[tid][2] = v.z; s_box[tid][3] = v.w;
    s_gmax[tid] = g_gtmax[b * NG + tid];
    s_cls[tid] = tcls[b * NG + tid];
  }
  __syncthreads();

  int k = blockIdx.x * 256 + tid;
  int cnt = 0;
  if (k < KTOT) {
    int l = lvl_of(k);
    int r = k - L_OFF[l];
    float ax0, ay0, ax1, ay1;
    anchor_box(l, r, ax0, ay0, ax1, ay1);
    bool inside = (ax0 >= 0.0f) & (ay0 >= 0.0f) & (ax1 <= 800.0f) & (ay1 <= 800.0f);
    float areaA = (ax1 - ax0) * (ay1 - ay0);

    float best = -2.0f;
    int arg = 0;
    int lqg = -1;
    for (int g = 0; g < NG; ++g) {
      float iou = inside ? iou_one(ax0, ay0, ax1, ay1, areaA,
                                   s_box[g][0], s_box[g][1], s_box[g][2], s_box[g][3])
                         : -1.0f;
      if (iou > best) { best = iou; arg = g; }       // first max wins (jnp.argmax)
      unsigned e = encf(iou);
      unsigned gm = s_gmax[g];
      if (e == gm && gm > 0x80000000u) lqg = g;      // last g wins (.max over arange)
    }
    int lab = (best >= 0.5f) ? 1 : ((best >= 0.4f) ? -1 : 0);
    int mg = arg;
    if (lqg >= 0) { lab = 1; mg = lqg; }
    bool pos = (lab == 1) && inside;
    bool neg = (lab == 0) && inside;

    int widx = L_WSB[l] + b * L_K[l] + r;
    g_lab[widx] = pos ? (int8_t)s_cls[mg] : (int8_t)0;
    g_lw[widx] = (pos || neg) ? 1 : 0;
    g_pos[widx] = pos ? 1 : 0;
    g_mg[widx] = (int8_t)mg;
    cnt = (pos || neg) ? 1 : 0;
  }
  unsigned long long m = __ballot(cnt != 0);
  if ((tid & 63) == 0 && m) atomicAdd(&s_cnt, (unsigned)__popcll(m));
  __syncthreads();
  if (tid == 0 && s_cnt) atomicAdd(&g_ns, s_cnt);
}

// ---------------- kernel 3: fused cls + bbox loss ----------------
template <int HW, int KL, int WSB>
DEVINL float cls_term(const float* __restrict__ cls, int idx) {
  constexpr int CHW = 72 * HW;
  constexpr int N = 8 * KL;
  int b = idx / CHW;
  int r0 = idx - b * CHW;
  int ch = r0 / HW;
  int pix = r0 - ch * HW;
  int a = ch >> 3;
  int c = ch & 7;
  int i = b * KL + pix * 9 + a;
  int v = 8 * i + c;
  int widx = v % N; // scrambled weight index from tile(lw,8).reshape(-1,8)
  float w = (float)g_lw[WSB + widx];
  if (w == 0.0f) return 0.0f;
  float x = cls[idx];
  int lab = g_lab[WSB + i];
  float t = (lab == c) ? 1.0f : 0.0f;
  float ax = fabsf(x);
  return (fmaxf(x, 0.0f) - x * t + log1pf(expf(-ax))) * w;
}

template <int W, int HW, int KL, int WSB, int STR>
DEVINL float box_term(const float* __restrict__ reg, int idx,
                      const float* __restrict__ tb) {
  constexpr int CHW = 36 * HW;
  int b = idx / CHW;
  int r0 = idx - b * CHW;
  int ch = r0 / HW;
  int pix = r0 - ch * HW;
  int a = ch >> 2;
  int d = ch & 3;
  int i = b * KL + pix * 9 + a;
  if (!g_pos[WSB + i]) return 0.0f;
  float pred = reg[idx];
  int mg = g_mg[WSB + i];
  int y = pix / W;
  int x = pix - y * W;
  int ridx = a / 3;
  int sidx = a - ridx * 3;
  double wsz = WR_T[ridx] * SC_T[sidx] * (double)STR;
  double hsz = HR_T[ridx] * SC_T[sidx] * (double)STR;
  double cx = (double)(x * STR);
  double cy = (double)(y * STR);
  float ax0 = (float)(cx - wsz * 0.5);
  float ay0 = (float)(cy - hsz * 0.5);
  float ax1 = (float)(cx + wsz * 0.5);
  float ay1 = (float)(cy + hsz * 0.5);
  float aw = ax1 - ax0, ah = ay1 - ay0;
  float acx = ax0 + 0.5f * aw, acy = ay0 + 0.5f * ah;
  float4 gb = reinterpret_cast<const float4*>(tb)[b * NG + mg];
  float gw = gb.z - gb.x, gh = gb.w - gb.y;
  float gcx = gb.x + 0.5f * gw, gcy = gb.y + 0.5f * gh;
  float t;
  if (d == 0) t = (gcx - acx) / aw;
  else if (d == 1) t = (gcy - acy) / ah;
  else if (d == 2) t = logf(gw / aw);
  else t = logf(gh / ah);
  return fabsf(pred - t);
}

__global__ __launch_bounds__(256) void k_loss(
    const float* __restrict__ c0, const float* __restrict__ c1,
    const float* __restrict__ c2, const float* __restrict__ c3,
    const float* __restrict__ c4, const float* __restrict__ r0,
    const float* __restrict__ r1, const float* __restrict__ r2,
    const float* __restrict__ r3, const float* __restrict__ r4,
    const float* __restrict__ tb) {
  int tid = blockIdx.x * 256 + threadIdx.x;
  float vc = 0.0f, vb = 0.0f;
  if (tid < C_OFF[5]) {
    if (tid < C_OFF[1])       vc = cls_term<10000, 90000, 0>(c0, tid);
    else if (tid < C_OFF[2])  vc = cls_term<2500, 22500, 720000>(c1, tid - C_OFF[1]);
    else if (tid < C_OFF[3])  vc = cls_term<625, 5625, 900000>(c2, tid - C_OFF[2]);
    else if (tid < C_OFF[4])  vc = cls_term<169, 1521, 945000>(c3, tid - C_OFF[3]);
    else                      vc = cls_term<49, 441, 957168>(c4, tid - C_OFF[4]);
  } else if (tid < TOTAL_E) {
    int t2 = tid - C_OFF[5];
    if (t2 < R_OFF[1])        vb = box_term<100, 10000, 90000, 0, 8>(r0, t2, tb);
    else if (t2 < R_OFF[2])   vb = box_term<50, 2500, 22500, 720000, 16>(r1, t2 - R_OFF[1], tb);
    else if (t2 < R_OFF[3])   vb = box_term<25, 625, 5625, 900000, 32>(r2, t2 - R_OFF[2], tb);
    else if (t2 < R_OFF[4])   vb = box_term<13, 169, 1521, 945000, 64>(r3, t2 - R_OFF[3], tb);
    else                      vb = box_term<7, 49, 441, 957168, 128>(r4, t2 - R_OFF[4], tb);
  }
  // block reduction (4 waves of 64)
  for (int off = 32; off; off >>= 1) {
    vc += __shfl_down(vc, off);
    vb += __shfl_down(vb, off);
  }
  __shared__ float sc_[4], sb_[4];
  int lane = threadIdx.x & 63;
  int wid = threadIdx.x >> 6;
  if (lane == 0) { sc_[wid] = vc; sb_[wid] = vb; }
  __syncthreads();
  if (threadIdx.x == 0) {
    float tc = sc_[0] + sc_[1] + sc_[2] + sc_[3];
    float tbx = sb_[0] + sb_[1] + sb_[2] + sb_[3];
    if (tc != 0.0f) atomicAdd(&g_acc[0], (double)tc);
    if (tbx != 0.0f) atomicAdd(&g_acc[1], (double)tbx);
  }
}

// ---------------- kernel 4: finalize ----------------
__global__ void k_fin(float* __restrict__ out) {
  if (threadIdx.x == 0) {
    double n = (double)g_ns;
    out[0] = (float)(g_acc[0] / n);
    out[1] = (float)(g_acc[1] / n);
  }
}

// ---------------- launcher ----------------
extern "C" void kernel_launch(void* const* d_in, const int* in_sizes, int n_in,
                              void* d_out, int out_size, void* d_ws, size_t ws_size,
                              hipStream_t stream) {
  // setup_inputs() inserts cls/reg INTERLEAVED: cls0,reg0,cls1,reg1,...,tb,tcls
  const float* c0 = (const float*)d_in[0];
  const float* r0 = (const float*)d_in[1];
  const float* c1 = (const float*)d_in[2];
  const float* r1 = (const float*)d_in[3];
  const float* c2 = (const float*)d_in[4];
  const float* r2 = (const float*)d_in[5];
  const float* c3 = (const float*)d_in[6];
  const float* r3 = (const float*)d_in[7];
  const float* c4 = (const float*)d_in[8];
  const float* r4 = (const float*)d_in[9];
  const float* tb = (const float*)d_in[10];
  const int* tcls = (const int*)d_in[11];
  float* out = (float*)d_out;

  k_init<<<dim3(1), dim3(512), 0, stream>>>();
  k_gtmax<<<dim3((KTOT + 256 * AP - 1) / (256 * AP), NB), dim3(256), 0, stream>>>(tb);
  k_assign<<<dim3((KTOT + 255) / 256, NB), dim3(256), 0, stream>>>(tb, tcls);
  k_loss<<<dim3((TOTAL_E + 255) / 256), dim3(256), 0, stream>>>(c0, c1, c2, c3, c4, r0, r1, r2,
                                                                r3, r4, tb);
  k_fin<<<dim3(1), dim3(64), 0, stream>>>(out);
}

// Round 3
// 444.102 us; speedup vs baseline: 1.7453x; 1.7453x over previous
//
#include <hip/hip_runtime.h>
#include <cstdint>

#define DEVINL __device__ __forceinline__

// ---------------- problem geometry ----------------
constexpr int NB = 8;        // batch
constexpr int NG = 50;       // gts per image
constexpr int KTOT = 120087; // total anchors per image
constexpr int BK = NB * KTOT;

constexpr int L_W[5]   = {100, 50, 25, 13, 7};
constexpr int L_K[5]   = {90000, 22500, 5625, 1521, 441};
constexpr int L_OFF[5] = {0, 90000, 112500, 118125, 119646};
constexpr int L_STR[5] = {8, 16, 32, 64, 128};
constexpr int L_WSB[5] = {0, 720000, 900000, 945000, 957168}; // L_OFF * NB

// base anchor tables (float64, matching numpy bit-for-bit)
constexpr double HR_T[3] = {0.7071067811865476, 1.0, 1.4142135623730951}; // sqrt(ratios)
constexpr double WR_T[3] = {1.0 / HR_T[0], 1.0, 1.0 / HR_T[2]};          // 1/sqrt(ratios)
constexpr double SC_T[3] = {4.0, 5.039684199579493, 6.3496042078727974}; // 4*2^(i/3)

// ---------------- device-global scratch ----------------
__device__ float4 g_anc[KTOT];        // precomputed f32 anchors (shared by ALL passes)
__device__ double g_accs[256][2];     // hashed loss accumulators
__device__ unsigned g_ns;
__device__ unsigned g_gtmax[NB * NG];
__device__ int8_t g_lab[BK];
__device__ int8_t g_lw[BK];
__device__ int8_t g_pos[BK];
__device__ int8_t g_mg[BK];

// ---------------- helpers ----------------
// monotonic float -> unsigned mapping (order- and equality-preserving)
DEVINL unsigned encf(float f) {
  unsigned u = __float_as_uint(f);
  return (u & 0x80000000u) ? ~u : (u | 0x80000000u);
}
// enc(+0.0f)=0x80000000; enc(-1.0f)=0x407FFFFF; iou>0 <=> enc(iou)>0x80000000u

DEVINL int lvl_of(int k) {
  return (k < 90000) ? 0 : (k < 112500) ? 1 : (k < 118125) ? 2 : (k < 119646) ? 3 : 4;
}

// the ONLY IoU expression (identical operand values in pass A and pass B)
DEVINL float iou_one(float ax0, float ay0, float ax1, float ay1, float areaA,
                     float bx0, float by0, float bx1, float by1, float areaB) {
  float ltx = fmaxf(ax0, bx0);
  float lty = fmaxf(ay0, by0);
  float rbx = fminf(ax1, bx1);
  float rby = fminf(ay1, by1);
  float wx = fmaxf(rbx - ltx, 0.0f);
  float wy = fmaxf(rby - lty, 0.0f);
  float inter = wx * wy;
  return inter / (areaA + areaB - inter);
}

// ---------------- kernel 0: init scratch ----------------
__global__ __launch_bounds__(512) void k_init() {
  int t = threadIdx.x;
  if (t < 256) { g_accs[t][0] = 0.0; g_accs[t][1] = 0.0; }
  if (t < NB * NG) g_gtmax[t] = 0u; // 0 < enc(-1.0f), valid floor
  if (t == 0) g_ns = 0u;
}

// ---------------- kernel 1: precompute anchors (f64 math once) ----------------
__global__ __launch_bounds__(256) void k_anchors() {
  int k = blockIdx.x * 256 + threadIdx.x;
  if (k >= KTOT) return;
  int l = lvl_of(k);
  int r = k - L_OFF[l];
  int loc = r / 9;
  int a = r - loc * 9;
  int W = L_W[l];
  int y = loc / W;
  int x = loc - y * W;
  int st = L_STR[l];
  int ridx = a / 3;
  int sidx = a - ridx * 3;
  double wsz = WR_T[ridx] * SC_T[sidx] * (double)st;
  double hsz = HR_T[ridx] * SC_T[sidx] * (double)st;
  double cx = (double)(x * st);
  double cy = (double)(y * st);
  g_anc[k] = make_float4((float)(cx - wsz * 0.5), (float)(cy - hsz * 0.5),
                         (float)(cx + wsz * 0.5), (float)(cy + hsz * 0.5));
}

// ---------------- kernel 2: per-(b,g) max IoU over anchors (pass A) ----------------
constexpr int AP = 4; // anchors per thread
__global__ __launch_bounds__(256) void k_gtmax(const float* __restrict__ tb) {
  const int b = blockIdx.y;
  __shared__ float s_b[NG][5]; // x0,y0,x1,y1,area
  int tid = threadIdx.x;
  if (tid < NG) {
    float4 v = reinterpret_cast<const float4*>(tb)[b * NG + tid];
    s_b[tid][0] = v.x; s_b[tid][1] = v.y; s_b[tid][2] = v.z; s_b[tid][3] = v.w;
    s_b[tid][4] = (v.z - v.x) * (v.w - v.y);
  }
  __syncthreads();

  unsigned gmax[NG];
#pragma unroll
  for (int g = 0; g < NG; ++g) gmax[g] = 0u;

  int base = blockIdx.x * (256 * AP) + tid;
#pragma unroll
  for (int j = 0; j < AP; ++j) {
    int k = base + j * 256;
    bool valid = k < KTOT;
    float4 A = g_anc[valid ? k : 0];
    bool inside = valid & (A.x >= 0.0f) & (A.y >= 0.0f) & (A.z <= 800.0f) & (A.w <= 800.0f);
    float areaA = (A.z - A.x) * (A.w - A.y);
#pragma unroll
    for (int g = 0; g < NG; ++g) {
      float iou = inside ? iou_one(A.x, A.y, A.z, A.w, areaA,
                                   s_b[g][0], s_b[g][1], s_b[g][2], s_b[g][3], s_b[g][4])
                         : -1.0f;
      unsigned e = encf(iou);
      gmax[g] = gmax[g] > e ? gmax[g] : e;
    }
  }
  // wave-reduce each g, one global atomic per wave (all loops statically indexed)
#pragma unroll
  for (int g = 0; g < NG; ++g) {
    unsigned v = gmax[g];
#pragma unroll
    for (int off = 32; off; off >>= 1) {
      unsigned o = (unsigned)__shfl_down((int)v, off);
      v = v > o ? v : o;
    }
    if ((tid & 63) == 0) atomicMax(&g_gtmax[b * NG + g], v);
  }
}

// ---------------- kernel 3: assignment (pass B) ----------------
__global__ __launch_bounds__(256) void k_assign(const float* __restrict__ tb,
                                                const int* __restrict__ tcls) {
  const int b = blockIdx.y;
  __shared__ float s_b[NG][5];
  __shared__ unsigned s_gmax[NG];
  __shared__ int s_cls[NG];
  __shared__ unsigned s_cnt;
  int tid = threadIdx.x;
  if (tid == 0) s_cnt = 0u;
  if (tid < NG) {
    float4 v = reinterpret_cast<const float4*>(tb)[b * NG + tid];
    s_b[tid][0] = v.x; s_b[tid][1] = v.y; s_b[tid][2] = v.z; s_b[tid][3] = v.w;
    s_b[tid][4] = (v.z - v.x) * (v.w - v.y);
    s_gmax[tid] = g_gtmax[b * NG + tid];
    s_cls[tid] = tcls[b * NG + tid];
  }
  __syncthreads();

  int k = blockIdx.x * 256 + tid;
  int cnt = 0;
  if (k < KTOT) {
    float4 A = g_anc[k];
    bool inside = (A.x >= 0.0f) & (A.y >= 0.0f) & (A.z <= 800.0f) & (A.w <= 800.0f);
    float areaA = (A.z - A.x) * (A.w - A.y);

    float best = -2.0f;
    int arg = 0;
    int lqg = -1;
    for (int g = 0; g < NG; ++g) {
      float iou = inside ? iou_one(A.x, A.y, A.z, A.w, areaA,
                                   s_b[g][0], s_b[g][1], s_b[g][2], s_b[g][3], s_b[g][4])
                         : -1.0f;
      if (iou > best) { best = iou; arg = g; }       // first max wins (jnp.argmax)
      unsigned e = encf(iou);
      unsigned gm = s_gmax[g];
      if (e == gm && gm > 0x80000000u) lqg = g;      // last g wins (.max over arange)
    }
    int lab = (best >= 0.5f) ? 1 : ((best >= 0.4f) ? -1 : 0);
    int mg = arg;
    if (lqg >= 0) { lab = 1; mg = lqg; }
    bool pos = (lab == 1) && inside;
    bool neg = (lab == 0) && inside;

    int l = lvl_of(k);
    int r = k - L_OFF[l];
    int widx = L_WSB[l] + b * L_K[l] + r;
    g_lab[widx] = pos ? (int8_t)s_cls[mg] : (int8_t)0;
    g_lw[widx] = (pos || neg) ? 1 : 0;
    g_pos[widx] = pos ? 1 : 0;
    g_mg[widx] = (int8_t)mg;
    cnt = (pos || neg) ? 1 : 0;
  }
  unsigned long long m = __ballot(cnt != 0);
  if ((tid & 63) == 0 && m) atomicAdd(&s_cnt, (unsigned)__popcll(m));
  __syncthreads();
  if (tid == 0 && s_cnt) atomicAdd(&g_ns, s_cnt);
}

// ---------------- kernel 4: fused cls + bbox loss, thread-per-anchor-slot ----------
// Per level: threads enumerate (b, a, pix) with pix fastest (coalesced loads).
// q = pix*9 + a; per-anchor array idx = WSB + b*KL + q.
// Scrambled cls weight (i,c) = lw[(8i+c) mod 8KL] = lw[8q+c]  (b-independent,
// 8B-aligned, never wraps since 8q is a multiple of 8 and < 8KL-7).
template <int HW, int KL, int WSB, int LOFF>
DEVINL void level_term(const float* __restrict__ cls, const float* __restrict__ reg,
                       const float4* __restrict__ tb4, int j, bool valid,
                       float& vc, float& vb) {
  constexpr int NHW9 = 9 * HW;
  int b = j / NHW9;
  int r2 = j - b * NHW9;
  int a = r2 / HW;
  int pix = r2 - a * HW;
  int q = pix * 9 + a;
  int idx = WSB + b * KL + q;

  unsigned long long lwq =
      *reinterpret_cast<const unsigned long long*>(&g_lw[WSB + 8 * q]);
  int lab = g_lab[idx];
  const float* cbase = cls + (b * 72 + a * 8) * HW + pix;
  if (valid && lwq) {
#pragma unroll
    for (int c = 0; c < 8; ++c) {
      float w = (float)((unsigned)(lwq >> (8 * c)) & 0xffu);
      float x = cbase[c * HW];
      float t = (lab == c) ? 1.0f : 0.0f;
      float ax = fabsf(x);
      float e = __expf(-ax);
      float bce = fmaxf(x, 0.0f) - x * t + __logf(1.0f + e);
      vc += bce * w;
    }
  }
  int posb = valid ? g_pos[idx] : 0;
  if (posb) {
    int mg = g_mg[idx];
    float4 A = g_anc[LOFF + q];
    float aw = A.z - A.x, ah = A.w - A.y;
    float acx = A.x + 0.5f * aw, acy = A.y + 0.5f * ah;
    float4 gb = tb4[b * NG + mg];
    float gw = gb.z - gb.x, gh = gb.w - gb.y;
    float gcx = gb.x + 0.5f * gw, gcy = gb.y + 0.5f * gh;
    const float* rbase = reg + (b * 36 + a * 4) * HW + pix;
    vb += fabsf(rbase[0] - (gcx - acx) / aw);
    vb += fabsf(rbase[HW] - (gcy - acy) / ah);
    vb += fabsf(rbase[2 * HW] - logf(gw / aw));
    vb += fabsf(rbase[3 * HW] - logf(gh / ah));
  }
}

__global__ __launch_bounds__(256) void k_loss(
    const float* __restrict__ c0, const float* __restrict__ c1,
    const float* __restrict__ c2, const float* __restrict__ c3,
    const float* __restrict__ c4, const float* __restrict__ r0,
    const float* __restrict__ r1, const float* __restrict__ r2,
    const float* __restrict__ r3, const float* __restrict__ r4,
    const float* __restrict__ tb) {
  const float4* tb4 = reinterpret_cast<const float4*>(tb);
  int T = blockIdx.x * 256 + threadIdx.x;
  bool valid = T < BK;
  int Tc = valid ? T : 0;
  float vc = 0.0f, vb = 0.0f;
  if (Tc < 720000)       level_term<10000, 90000, 0, 0>(c0, r0, tb4, Tc, valid, vc, vb);
  else if (Tc < 900000)  level_term<2500, 22500, 720000, 90000>(c1, r1, tb4, Tc - 720000, valid, vc, vb);
  else if (Tc < 945000)  level_term<625, 5625, 900000, 112500>(c2, r2, tb4, Tc - 900000, valid, vc, vb);
  else if (Tc < 957168)  level_term<169, 1521, 945000, 118125>(c3, r3, tb4, Tc - 945000, valid, vc, vb);
  else                   level_term<49, 441, 957168, 119646>(c4, r4, tb4, Tc - 957168, valid, vc, vb);

  // block reduction (4 waves of 64)
#pragma unroll
  for (int off = 32; off; off >>= 1) {
    vc += __shfl_down(vc, off);
    vb += __shfl_down(vb, off);
  }
  __shared__ float sc_[4], sb_[4];
  int lane = threadIdx.x & 63;
  int wid = threadIdx.x >> 6;
  if (lane == 0) { sc_[wid] = vc; sb_[wid] = vb; }
  __syncthreads();
  if (threadIdx.x == 0) {
    float tc = sc_[0] + sc_[1] + sc_[2] + sc_[3];
    float tbx = sb_[0] + sb_[1] + sb_[2] + sb_[3];
    int slot = blockIdx.x & 255; // hashed slots: ~15 blocks/slot, no hot address
    if (tc != 0.0f) atomicAdd(&g_accs[slot][0], (double)tc);
    if (tbx != 0.0f) atomicAdd(&g_accs[slot][1], (double)tbx);
  }
}

// ---------------- kernel 5: finalize ----------------
__global__ __launch_bounds__(256) void k_fin(float* __restrict__ out) {
  int t = threadIdx.x;
  double a0 = g_accs[t][0];
  double a1 = g_accs[t][1];
#pragma unroll
  for (int off = 32; off; off >>= 1) {
    a0 += __shfl_down(a0, off);
    a1 += __shfl_down(a1, off);
  }
  __shared__ double s0[4], s1[4];
  if ((t & 63) == 0) { s0[t >> 6] = a0; s1[t >> 6] = a1; }
  __syncthreads();
  if (t == 0) {
    double A0 = s0[0] + s0[1] + s0[2] + s0[3];
    double A1 = s1[0] + s1[1] + s1[2] + s1[3];
    double n = (double)g_ns;
    out[0] = (float)(A0 / n);
    out[1] = (float)(A1 / n);
  }
}

// ---------------- launcher ----------------
extern "C" void kernel_launch(void* const* d_in, const int* in_sizes, int n_in,
                              void* d_out, int out_size, void* d_ws, size_t ws_size,
                              hipStream_t stream) {
  // setup_inputs() inserts cls/reg INTERLEAVED: cls0,reg0,cls1,reg1,...,tb,tcls
  const float* c0 = (const float*)d_in[0];
  const float* r0 = (const float*)d_in[1];
  const float* c1 = (const float*)d_in[2];
  const float* r1 = (const float*)d_in[3];
  const float* c2 = (const float*)d_in[4];
  const float* r2 = (const float*)d_in[5];
  const float* c3 = (const float*)d_in[6];
  const float* r3 = (const float*)d_in[7];
  const float* c4 = (const float*)d_in[8];
  const float* r4 = (const float*)d_in[9];
  const float* tb = (const float*)d_in[10];
  const int* tcls = (const int*)d_in[11];
  float* out = (float*)d_out;

  k_init<<<dim3(1), dim3(512), 0, stream>>>();
  k_anchors<<<dim3((KTOT + 255) / 256), dim3(256), 0, stream>>>();
  k_gtmax<<<dim3((KTOT + 256 * AP - 1) / (256 * AP), NB), dim3(256), 0, stream>>>(tb);
  k_assign<<<dim3((KTOT + 255) / 256, NB), dim3(256), 0, stream>>>(tb, tcls);
  k_loss<<<dim3((BK + 255) / 256), dim3(256), 0, stream>>>(c0, c1, c2, c3, c4, r0, r1, r2,
                                                           r3, r4, tb);
  k_fin<<<dim3(1), dim3(256), 0, stream>>>(out);
}

// Round 4
// 198.826 us; speedup vs baseline: 3.8983x; 2.2336x over previous
//
#include <hip/hip_runtime.h>
#include <cstdint>

#define DEVINL __device__ __forceinline__

// ---------------- problem geometry ----------------
constexpr int NB = 8;        // batch
constexpr int NG = 50;       // gts per image
constexpr int KTOT = 120087; // total anchors per image
constexpr int BK = NB * KTOT;

constexpr int L_W[5]   = {100, 50, 25, 13, 7};
constexpr int L_K[5]   = {90000, 22500, 5625, 1521, 441};
constexpr int L_OFF[5] = {0, 90000, 112500, 118125, 119646};
constexpr int L_STR[5] = {8, 16, 32, 64, 128};
constexpr int L_WSB[5] = {0, 720000, 900000, 945000, 957168}; // L_OFF * NB

// base anchor tables (float64, matching numpy bit-for-bit)
constexpr double HR_T[3] = {0.7071067811865476, 1.0, 1.4142135623730951}; // sqrt(ratios)
constexpr double WR_T[3] = {1.0 / HR_T[0], 1.0, 1.0 / HR_T[2]};          // 1/sqrt(ratios)
constexpr double SC_T[3] = {4.0, 5.039684199579493, 6.3496042078727974}; // 4*2^(i/3)

// ---------------- device-global scratch ----------------
__device__ float4 g_anc[KTOT];        // precomputed f32 anchors (shared by ALL passes)
__device__ double g_accs[256][2];     // hashed loss accumulators
__device__ unsigned g_ns;
__device__ unsigned g_gtmax[NB * NG];
__device__ int8_t g_lab[BK];
__device__ int8_t g_lw[BK];
__device__ int8_t g_pos[BK];
__device__ int8_t g_mg[BK];

// ---------------- helpers ----------------
// monotonic float -> unsigned mapping (order- and equality-preserving)
DEVINL unsigned encf(float f) {
  unsigned u = __float_as_uint(f);
  return (u & 0x80000000u) ? ~u : (u | 0x80000000u);
}
// enc(+0.0f)=0x80000000; iou>0 <=> enc(iou)>0x80000000u

DEVINL int lvl_of(int k) {
  return (k < 90000) ? 0 : (k < 112500) ? 1 : (k < 118125) ? 2 : (k < 119646) ? 3 : 4;
}

// the ONLY IoU expression — fast division, identical sequence in pass A and B
DEVINL float iou_one(float ax0, float ay0, float ax1, float ay1, float areaA,
                     float bx0, float by0, float bx1, float by1, float areaB) {
  float ltx = fmaxf(ax0, bx0);
  float lty = fmaxf(ay0, by0);
  float rbx = fminf(ax1, bx1);
  float rby = fminf(ay1, by1);
  float wx = fmaxf(rbx - ltx, 0.0f);
  float wy = fmaxf(rby - lty, 0.0f);
  float inter = wx * wy;
  return __fdividef(inter, areaA + areaB - inter);
}

// ---------------- kernel 0: init scratch ----------------
__global__ __launch_bounds__(512) void k_init() {
  int t = threadIdx.x;
  if (t < 256) { g_accs[t][0] = 0.0; g_accs[t][1] = 0.0; }
  if (t < NB * NG) g_gtmax[t] = 0u;
  if (t == 0) g_ns = 0u;
}

// ---------------- kernel 1: precompute anchors (f64 math once) ----------------
__global__ __launch_bounds__(256) void k_anchors() {
  int k = blockIdx.x * 256 + threadIdx.x;
  if (k >= KTOT) return;
  int l = lvl_of(k);
  int r = k - L_OFF[l];
  int loc = r / 9;
  int a = r - loc * 9;
  int W = L_W[l];
  int y = loc / W;
  int x = loc - y * W;
  int st = L_STR[l];
  int ridx = a / 3;
  int sidx = a - ridx * 3;
  double wsz = WR_T[ridx] * SC_T[sidx] * (double)st;
  double hsz = HR_T[ridx] * SC_T[sidx] * (double)st;
  double cx = (double)(x * st);
  double cy = (double)(y * st);
  g_anc[k] = make_float4((float)(cx - wsz * 0.5), (float)(cy - hsz * 0.5),
                         (float)(cx + wsz * 0.5), (float)(cy + hsz * 0.5));
}

// ---------------- kernel 2: per-(b,g) max IoU over anchors (pass A) ----------------
// g-chunked: blockIdx.z picks 10 of the 50 gts; boxes live in registers;
// unrolled body ~5KB (fits I$, unlike the old 48KB 200-IoU body).
constexpr int AP = 4;   // anchors per thread
constexpr int GCH = 10; // gts per chunk
constexpr int GZ = 5;   // chunks (GCH*GZ == NG)
__global__ __launch_bounds__(256) void k_gtmax(const float* __restrict__ tb) {
  const int b = blockIdx.y;
  const int g0 = blockIdx.z * GCH;
  // boxes for this chunk -> registers (uniform across block, L1-broadcast)
  float bx0[GCH], by0[GCH], bx1[GCH], by1[GCH], bar[GCH];
#pragma unroll
  for (int i = 0; i < GCH; ++i) {
    float4 v = reinterpret_cast<const float4*>(tb)[b * NG + g0 + i];
    bx0[i] = v.x; by0[i] = v.y; bx1[i] = v.z; by1[i] = v.w;
    bar[i] = (v.z - v.x) * (v.w - v.y);
  }
  float gmax[GCH];
#pragma unroll
  for (int i = 0; i < GCH; ++i) gmax[i] = -1.0f;

  int base = blockIdx.x * (256 * AP) + threadIdx.x;
#pragma unroll
  for (int j = 0; j < AP; ++j) {
    int k = base + j * 256;
    bool valid = k < KTOT;
    float4 A = g_anc[valid ? k : 0];
    bool inside = valid & (A.x >= 0.0f) & (A.y >= 0.0f) & (A.z <= 800.0f) & (A.w <= 800.0f);
    float areaA = (A.z - A.x) * (A.w - A.y);
#pragma unroll
    for (int i = 0; i < GCH; ++i) {
      float iou = inside ? iou_one(A.x, A.y, A.z, A.w, areaA,
                                   bx0[i], by0[i], bx1[i], by1[i], bar[i])
                         : -1.0f;
      gmax[i] = fmaxf(gmax[i], iou);
    }
  }
  // wave reduce (float-domain max == unsigned-domain max after encf; encode once)
  __shared__ unsigned s_red[4][GCH];
  int lane = threadIdx.x & 63, wid = threadIdx.x >> 6;
#pragma unroll
  for (int i = 0; i < GCH; ++i) {
    unsigned v = encf(gmax[i]);
#pragma unroll
    for (int off = 32; off; off >>= 1) {
      unsigned o = (unsigned)__shfl_down((int)v, off);
      v = v > o ? v : o;
    }
    if (lane == 0) s_red[wid][i] = v;
  }
  __syncthreads();
  if (threadIdx.x < GCH) {
    unsigned v = s_red[0][threadIdx.x];
#pragma unroll
    for (int w = 1; w < 4; ++w) { unsigned o = s_red[w][threadIdx.x]; v = v > o ? v : o; }
    atomicMax(&g_gtmax[b * NG + g0 + threadIdx.x], v);
  }
}

// ---------------- kernel 3: assignment (pass B) ----------------
__global__ __launch_bounds__(256) void k_assign(const float* __restrict__ tb,
                                                const int* __restrict__ tcls) {
  const int b = blockIdx.y;
  __shared__ float s_b[NG][5];
  __shared__ float s_qmax[NG]; // decoded gt_max if >0, else NaN (== never true)
  __shared__ int s_cls[NG];
  __shared__ unsigned s_cnt;
  int tid = threadIdx.x;
  if (tid == 0) s_cnt = 0u;
  if (tid < NG) {
    float4 v = reinterpret_cast<const float4*>(tb)[b * NG + tid];
    s_b[tid][0] = v.x; s_b[tid][1] = v.y; s_b[tid][2] = v.z; s_b[tid][3] = v.w;
    s_b[tid][4] = (v.z - v.x) * (v.w - v.y);
    unsigned gm = g_gtmax[b * NG + tid];
    s_qmax[tid] = (gm > 0x80000000u) ? __uint_as_float(gm ^ 0x80000000u)
                                     : __uint_as_float(0x7FC00000u);
    s_cls[tid] = tcls[b * NG + tid];
  }
  __syncthreads();

  int k = blockIdx.x * 256 + tid;
  int cnt = 0;
  if (k < KTOT) {
    float4 A = g_anc[k];
    bool inside = (A.x >= 0.0f) & (A.y >= 0.0f) & (A.z <= 800.0f) & (A.w <= 800.0f);
    float areaA = (A.z - A.x) * (A.w - A.y);

    float best = -2.0f;
    int arg = 0;
    int lqg = -1;
#pragma unroll 10
    for (int g = 0; g < NG; ++g) {
      float iou = inside ? iou_one(A.x, A.y, A.z, A.w, areaA,
                                   s_b[g][0], s_b[g][1], s_b[g][2], s_b[g][3], s_b[g][4])
                         : -1.0f;
      if (iou > best) { best = iou; arg = g; }  // first max wins (jnp.argmax)
      if (iou == s_qmax[g]) lqg = g;            // last g wins; NaN blocks gt_max<=0
    }
    int lab = (best >= 0.5f) ? 1 : ((best >= 0.4f) ? -1 : 0);
    int mg = arg;
    if (lqg >= 0) { lab = 1; mg = lqg; }
    bool pos = (lab == 1) && inside;
    bool neg = (lab == 0) && inside;

    int l = lvl_of(k);
    int r = k - L_OFF[l];
    int widx = L_WSB[l] + b * L_K[l] + r;
    g_lab[widx] = pos ? (int8_t)s_cls[mg] : (int8_t)0;
    g_lw[widx] = (pos || neg) ? 1 : 0;
    g_pos[widx] = pos ? 1 : 0;
    g_mg[widx] = (int8_t)mg;
    cnt = (pos || neg) ? 1 : 0;
  }
  unsigned long long m = __ballot(cnt != 0);
  if ((tid & 63) == 0 && m) atomicAdd(&s_cnt, (unsigned)__popcll(m));
  __syncthreads();
  if (tid == 0 && s_cnt) atomicAdd(&g_ns, s_cnt);
}

// ---------------- kernel 4: fused cls + bbox loss, thread-per-anchor-slot ----------
template <int HW, int KL, int WSB, int LOFF>
DEVINL void level_term(const float* __restrict__ cls, const float* __restrict__ reg,
                       const float4* __restrict__ tb4, int j, bool valid,
                       float& vc, float& vb) {
  constexpr int NHW9 = 9 * HW;
  int b = j / NHW9;
  int r2 = j - b * NHW9;
  int a = r2 / HW;
  int pix = r2 - a * HW;
  int q = pix * 9 + a;
  int idx = WSB + b * KL + q;

  unsigned long long lwq =
      *reinterpret_cast<const unsigned long long*>(&g_lw[WSB + 8 * q]);
  int lab = g_lab[idx];
  const float* cbase = cls + (b * 72 + a * 8) * HW + pix;
  if (valid && lwq) {
#pragma unroll
    for (int c = 0; c < 8; ++c) {
      float w = (float)((unsigned)(lwq >> (8 * c)) & 0xffu);
      float x = cbase[c * HW];
      float t = (lab == c) ? 1.0f : 0.0f;
      float ax = fabsf(x);
      float e = __expf(-ax);
      float bce = fmaxf(x, 0.0f) - x * t + __logf(1.0f + e);
      vc += bce * w;
    }
  }
  int posb = valid ? g_pos[idx] : 0;
  if (posb) {
    int mg = g_mg[idx];
    float4 A = g_anc[LOFF + q];
    float aw = A.z - A.x, ah = A.w - A.y;
    float acx = A.x + 0.5f * aw, acy = A.y + 0.5f * ah;
    float4 gb = tb4[b * NG + mg];
    float gw = gb.z - gb.x, gh = gb.w - gb.y;
    float gcx = gb.x + 0.5f * gw, gcy = gb.y + 0.5f * gh;
    const float* rbase = reg + (b * 36 + a * 4) * HW + pix;
    vb += fabsf(rbase[0] - (gcx - acx) / aw);
    vb += fabsf(rbase[HW] - (gcy - acy) / ah);
    vb += fabsf(rbase[2 * HW] - logf(gw / aw));
    vb += fabsf(rbase[3 * HW] - logf(gh / ah));
  }
}

__global__ __launch_bounds__(256) void k_loss(
    const float* __restrict__ c0, const float* __restrict__ c1,
    const float* __restrict__ c2, const float* __restrict__ c3,
    const float* __restrict__ c4, const float* __restrict__ r0,
    const float* __restrict__ r1, const float* __restrict__ r2,
    const float* __restrict__ r3, const float* __restrict__ r4,
    const float* __restrict__ tb) {
  const float4* tb4 = reinterpret_cast<const float4*>(tb);
  int T = blockIdx.x * 256 + threadIdx.x;
  bool valid = T < BK;
  int Tc = valid ? T : 0;
  float vc = 0.0f, vb = 0.0f;
  if (Tc < 720000)       level_term<10000, 90000, 0, 0>(c0, r0, tb4, Tc, valid, vc, vb);
  else if (Tc < 900000)  level_term<2500, 22500, 720000, 90000>(c1, r1, tb4, Tc - 720000, valid, vc, vb);
  else if (Tc < 945000)  level_term<625, 5625, 900000, 112500>(c2, r2, tb4, Tc - 900000, valid, vc, vb);
  else if (Tc < 957168)  level_term<169, 1521, 945000, 118125>(c3, r3, tb4, Tc - 945000, valid, vc, vb);
  else                   level_term<49, 441, 957168, 119646>(c4, r4, tb4, Tc - 957168, valid, vc, vb);

#pragma unroll
  for (int off = 32; off; off >>= 1) {
    vc += __shfl_down(vc, off);
    vb += __shfl_down(vb, off);
  }
  __shared__ float sc_[4], sb_[4];
  int lane = threadIdx.x & 63;
  int wid = threadIdx.x >> 6;
  if (lane == 0) { sc_[wid] = vc; sb_[wid] = vb; }
  __syncthreads();
  if (threadIdx.x == 0) {
    float tc = sc_[0] + sc_[1] + sc_[2] + sc_[3];
    float tbx = sb_[0] + sb_[1] + sb_[2] + sb_[3];
    int slot = blockIdx.x & 255;
    if (tc != 0.0f) atomicAdd(&g_accs[slot][0], (double)tc);
    if (tbx != 0.0f) atomicAdd(&g_accs[slot][1], (double)tbx);
  }
}

// ---------------- kernel 5: finalize ----------------
__global__ __launch_bounds__(256) void k_fin(float* __restrict__ out) {
  int t = threadIdx.x;
  double a0 = g_accs[t][0];
  double a1 = g_accs[t][1];
#pragma unroll
  for (int off = 32; off; off >>= 1) {
    a0 += __shfl_down(a0, off);
    a1 += __shfl_down(a1, off);
  }
  __shared__ double s0[4], s1[4];
  if ((t & 63) == 0) { s0[t >> 6] = a0; s1[t >> 6] = a1; }
  __syncthreads();
  if (t == 0) {
    double A0 = s0[0] + s0[1] + s0[2] + s0[3];
    double A1 = s1[0] + s1[1] + s1[2] + s1[3];
    double n = (double)g_ns;
    out[0] = (float)(A0 / n);
    out[1] = (float)(A1 / n);
  }
}

// ---------------- launcher ----------------
extern "C" void kernel_launch(void* const* d_in, const int* in_sizes, int n_in,
                              void* d_out, int out_size, void* d_ws, size_t ws_size,
                              hipStream_t stream) {
  // setup_inputs() inserts cls/reg INTERLEAVED: cls0,reg0,cls1,reg1,...,tb,tcls
  const float* c0 = (const float*)d_in[0];
  const float* r0 = (const float*)d_in[1];
  const float* c1 = (const float*)d_in[2];
  const float* r1 = (const float*)d_in[3];
  const float* c2 = (const float*)d_in[4];
  const float* r2 = (const float*)d_in[5];
  const float* c3 = (const float*)d_in[6];
  const float* r3 = (const float*)d_in[7];
  const float* c4 = (const float*)d_in[8];
  const float* r4 = (const float*)d_in[9];
  const float* tb = (const float*)d_in[10];
  const int* tcls = (const int*)d_in[11];
  float* out = (float*)d_out;

  k_init<<<dim3(1), dim3(512), 0, stream>>>();
  k_anchors<<<dim3((KTOT + 255) / 256), dim3(256), 0, stream>>>();
  k_gtmax<<<dim3((KTOT + 256 * AP - 1) / (256 * AP), NB, GZ), dim3(256), 0, stream>>>(tb);
  k_assign<<<dim3((KTOT + 255) / 256, NB), dim3(256), 0, stream>>>(tb, tcls);
  k_loss<<<dim3((BK + 255) / 256), dim3(256), 0, stream>>>(c0, c1, c2, c3, c4, r0, r1, r2,
                                                           r3, r4, tb);
  k_fin<<<dim3(1), dim3(256), 0, stream>>>(out);
}

// Round 5
// 166.161 us; speedup vs baseline: 4.6647x; 1.1966x over previous
//
#include <hip/hip_runtime.h>
#include <cstdint>

#define DEVINL __device__ __forceinline__

// ---------------- problem geometry ----------------
constexpr int NB = 8;        // batch
constexpr int NG = 50;       // gts per image
constexpr int KTOT = 120087; // total anchors per image
constexpr int BK = NB * KTOT;

constexpr int L_W[5]   = {100, 50, 25, 13, 7};
constexpr int L_K[5]   = {90000, 22500, 5625, 1521, 441};
constexpr int L_OFF[5] = {0, 90000, 112500, 118125, 119646};
constexpr int L_STR[5] = {8, 16, 32, 64, 128};
constexpr int L_WSB[5] = {0, 720000, 900000, 945000, 957168}; // L_OFF * NB

// base anchor tables (float64, matching numpy bit-for-bit)
constexpr double HR_T[3] = {0.7071067811865476, 1.0, 1.4142135623730951}; // sqrt(ratios)
constexpr double WR_T[3] = {1.0 / HR_T[0], 1.0, 1.0 / HR_T[2]};          // 1/sqrt(ratios)
constexpr double SC_T[3] = {4.0, 5.039684199579493, 6.3496042078727974}; // 4*2^(i/3)

// ---------------- device-global scratch ----------------
__device__ float4 g_anc[KTOT];        // precomputed f32 anchors (shared by ALL passes)
__device__ double g_accs[256][2];     // hashed loss accumulators
__device__ unsigned g_ns;
__device__ unsigned g_gtmax[NB * NG];
__device__ int8_t g_lab[BK];
__device__ __align__(8) int8_t g_lw[BK];
__device__ int8_t g_pos[BK];
__device__ int8_t g_mg[BK];

// ---------------- helpers ----------------
// monotonic float -> unsigned mapping (order- and equality-preserving)
DEVINL unsigned encf(float f) {
  unsigned u = __float_as_uint(f);
  return (u & 0x80000000u) ? ~u : (u | 0x80000000u);
}
// enc(+0.0f)=0x80000000; iou>0 <=> enc(iou)>0x80000000u

DEVINL int lvl_of(int k) {
  return (k < 90000) ? 0 : (k < 112500) ? 1 : (k < 118125) ? 2 : (k < 119646) ? 3 : 4;
}

// the ONLY IoU expression — identical instruction sequence everywhere
DEVINL float iou_one(float ax0, float ay0, float ax1, float ay1, float areaA,
                     float bx0, float by0, float bx1, float by1, float areaB) {
  float ltx = fmaxf(ax0, bx0);
  float lty = fmaxf(ay0, by0);
  float rbx = fminf(ax1, bx1);
  float rby = fminf(ay1, by1);
  float wx = fmaxf(rbx - ltx, 0.0f);
  float wy = fmaxf(rby - lty, 0.0f);
  float inter = wx * wy;
  return __fdividef(inter, areaA + areaB - inter);
}

// ---------------- kernel 0: setup (init scalars + precompute anchors) -------
__global__ __launch_bounds__(256) void k_setup() {
  if (blockIdx.x == 0) {
    int t = threadIdx.x;
    g_accs[t][0] = 0.0;
    g_accs[t][1] = 0.0;
    if (t == 0) g_ns = 0u;
  }
  int k = blockIdx.x * 256 + threadIdx.x;
  if (k >= KTOT) return;
  int l = lvl_of(k);
  int r = k - L_OFF[l];
  int loc = r / 9;
  int a = r - loc * 9;
  int W = L_W[l];
  int y = loc / W;
  int x = loc - y * W;
  int st = L_STR[l];
  int ridx = a / 3;
  int sidx = a - ridx * 3;
  double wsz = WR_T[ridx] * SC_T[sidx] * (double)st;
  double hsz = HR_T[ridx] * SC_T[sidx] * (double)st;
  double cx = (double)(x * st);
  double cy = (double)(y * st);
  g_anc[k] = make_float4((float)(cx - wsz * 0.5), (float)(cy - hsz * 0.5),
                         (float)(cx + wsz * 0.5), (float)(cy + hsz * 0.5));
}

// ---------------- kernel 1: analytic per-(b,g) gt_max ----------------------
// For fixed shape, 1D overlap ox(cx) is concave piecewise-linear in the anchor
// center, so the grid argmax (restricted to the inside-valid range) is among
// {floor,ceil of box center} ∪ {range bounds} per axis. We evaluate a 10x10
// candidate set per shape with the REAL g_anc values and the REAL iou_one,
// so the resulting max is bit-identical to brute-force.
DEVINL int axis_cand(int xi, int i0, int lo, int hi, int Wm1) {
  int c;
  if (xi < 4) c = i0 - 1 + xi;
  else if (xi == 4) c = lo;
  else if (xi == 5) c = lo + 1;
  else if (xi == 6) c = hi - 1;
  else if (xi == 7) c = hi;
  else if (xi == 8) c = 0;
  else c = Wm1;
  return min(max(c, 0), Wm1);
}

__global__ __launch_bounds__(256) void k_gtmax2(const float* __restrict__ tb) {
  const int bg = blockIdx.x; // b*NG + g
  float4 v = reinterpret_cast<const float4*>(tb)[bg];
  const float bx0 = v.x, by0 = v.y, bx1 = v.z, by1 = v.w;
  const float areaB = (bx1 - bx0) * (by1 - by0);
  const float bcx = 0.5f * (bx0 + bx1), bcy = 0.5f * (by0 + by1);

  float m = -1.0f;
  for (int t = threadIdx.x; t < 4500; t += 256) {
    int l = t / 900;
    int rem = t - l * 900;
    int a = rem / 100;
    int rem2 = rem - a * 100;
    int xi = rem2 / 10;
    int yi = rem2 - xi * 10;
    // level params via select chains (no runtime-indexed arrays)
    int W = (l == 0) ? 100 : (l == 1) ? 50 : (l == 2) ? 25 : (l == 3) ? 13 : 7;
    int loff = (l == 0) ? 0 : (l == 1) ? 90000 : (l == 2) ? 112500
               : (l == 3) ? 118125 : 119646;
    float stf = (float)(8 << l);
    float4 A0 = g_anc[loff + a]; // anchor at grid (0,0): A0.x = -w/2, A0.y = -h/2
    float whalf = -A0.x;
    float hhalf = -A0.y;
    int i0x = (int)floorf(bcx / stf);
    int lox = (int)ceilf(whalf / stf);
    int hix = (int)floorf((800.0f - whalf) / stf);
    int i0y = (int)floorf(bcy / stf);
    int loy = (int)ceilf(hhalf / stf);
    int hiy = (int)floorf((800.0f - hhalf) / stf);
    int cx = axis_cand(xi, i0x, lox, hix, W - 1);
    int cy = axis_cand(yi, i0y, loy, hiy, W - 1);
    int k = loff + (cy * W + cx) * 9 + a;
    float4 A = g_anc[k];
    bool inside = (A.x >= 0.0f) & (A.y >= 0.0f) & (A.z <= 800.0f) & (A.w <= 800.0f);
    float areaA = (A.z - A.x) * (A.w - A.y);
    float iou = inside ? iou_one(A.x, A.y, A.z, A.w, areaA,
                                 bx0, by0, bx1, by1, areaB)
                       : -1.0f;
    m = fmaxf(m, iou);
  }
  // reduce 256 -> 1
#pragma unroll
  for (int off = 32; off; off >>= 1) m = fmaxf(m, __shfl_down(m, off));
  __shared__ float s_m[4];
  int lane = threadIdx.x & 63, wid = threadIdx.x >> 6;
  if (lane == 0) s_m[wid] = m;
  __syncthreads();
  if (threadIdx.x == 0) {
    float r = fmaxf(fmaxf(s_m[0], s_m[1]), fmaxf(s_m[2], s_m[3]));
    g_gtmax[bg] = encf(r); // sole writer, no atomic
  }
}

// ---------------- kernel 2: assignment (pass B), AP anchors/thread ---------
constexpr int APB = 4;
__global__ __launch_bounds__(256) void k_assign(const float* __restrict__ tb,
                                                const int* __restrict__ tcls) {
  const int b = blockIdx.y;
  __shared__ float s_b[NG][8]; // x0,y0,x1,y1,area,qmax (rows 32B-aligned)
  __shared__ int s_cls[NG];
  __shared__ unsigned s_cnt;
  int tid = threadIdx.x;
  if (tid == 0) s_cnt = 0u;
  if (tid < NG) {
    float4 v = reinterpret_cast<const float4*>(tb)[b * NG + tid];
    s_b[tid][0] = v.x; s_b[tid][1] = v.y; s_b[tid][2] = v.z; s_b[tid][3] = v.w;
    s_b[tid][4] = (v.z - v.x) * (v.w - v.y);
    unsigned gm = g_gtmax[b * NG + tid];
    s_b[tid][5] = (gm > 0x80000000u) ? __uint_as_float(gm ^ 0x80000000u)
                                     : __uint_as_float(0x7FC00000u); // NaN: never ==
    s_cls[tid] = tcls[b * NG + tid];
  }
  __syncthreads();

  const int base = blockIdx.x * (256 * APB) + tid;
  float Ax0[APB], Ay0[APB], Ax1[APB], Ay1[APB], areaA[APB];
  bool inside[APB];
  float best[APB];
  int arg[APB], lqg[APB];
#pragma unroll
  for (int ap = 0; ap < APB; ++ap) {
    int k = base + ap * 256;
    bool valid = k < KTOT;
    float4 A = g_anc[valid ? k : 0];
    Ax0[ap] = A.x; Ay0[ap] = A.y; Ax1[ap] = A.z; Ay1[ap] = A.w;
    inside[ap] = valid & (A.x >= 0.0f) & (A.y >= 0.0f) & (A.z <= 800.0f) & (A.w <= 800.0f);
    areaA[ap] = (A.z - A.x) * (A.w - A.y);
    best[ap] = -2.0f; arg[ap] = 0; lqg[ap] = -1;
  }

#pragma unroll 5
  for (int g = 0; g < NG; ++g) {
    float gx0 = s_b[g][0], gy0 = s_b[g][1], gx1 = s_b[g][2], gy1 = s_b[g][3];
    float gar = s_b[g][4], qmx = s_b[g][5];
#pragma unroll
    for (int ap = 0; ap < APB; ++ap) {
      float iou = inside[ap] ? iou_one(Ax0[ap], Ay0[ap], Ax1[ap], Ay1[ap], areaA[ap],
                                       gx0, gy0, gx1, gy1, gar)
                             : -1.0f;
      if (iou > best[ap]) { best[ap] = iou; arg[ap] = g; } // first max wins
      if (iou == qmx) lqg[ap] = g;                         // last g wins
    }
  }

  int cnt = 0;
#pragma unroll
  for (int ap = 0; ap < APB; ++ap) {
    int k = base + ap * 256;
    if (k < KTOT) {
      int lab = (best[ap] >= 0.5f) ? 1 : ((best[ap] >= 0.4f) ? -1 : 0);
      int mg = arg[ap];
      if (lqg[ap] >= 0) { lab = 1; mg = lqg[ap]; }
      bool pos = (lab == 1) && inside[ap];
      bool neg = (lab == 0) && inside[ap];
      int l = lvl_of(k);
      int r = k - L_OFF[l];
      int widx = L_WSB[l] + b * L_K[l] + r;
      g_lab[widx] = pos ? (int8_t)s_cls[mg] : (int8_t)0;
      g_lw[widx] = (pos || neg) ? 1 : 0;
      g_pos[widx] = pos ? 1 : 0;
      g_mg[widx] = (int8_t)mg;
      cnt += (pos || neg) ? 1 : 0;
    }
  }
  // wave-sum then one LDS atomic per wave, one global atomic per block
#pragma unroll
  for (int off = 32; off; off >>= 1) cnt += __shfl_down(cnt, off);
  if ((tid & 63) == 0 && cnt) atomicAdd(&s_cnt, (unsigned)cnt);
  __syncthreads();
  if (tid == 0 && s_cnt) atomicAdd(&g_ns, s_cnt);
}

// ---------------- kernel 3: fused cls + bbox loss, thread-per-anchor-slot ----
template <int HW, int KL, int WSB, int LOFF>
DEVINL void level_term(const float* __restrict__ cls, const float* __restrict__ reg,
                       const float4* __restrict__ tb4, int j, bool valid,
                       float& vc, float& vb) {
  constexpr int NHW9 = 9 * HW;
  int b = j / NHW9;
  int r2 = j - b * NHW9;
  int a = r2 / HW;
  int pix = r2 - a * HW;
  int q = pix * 9 + a;
  int idx = WSB + b * KL + q;

  unsigned long long lwq =
      *reinterpret_cast<const unsigned long long*>(&g_lw[WSB + 8 * q]);
  int lab = g_lab[idx];
  const float* cbase = cls + (b * 72 + a * 8) * HW + pix;
  if (valid && lwq) {
#pragma unroll
    for (int c = 0; c < 8; ++c) {
      float w = (float)((unsigned)(lwq >> (8 * c)) & 0xffu);
      float x = cbase[c * HW];
      float t = (lab == c) ? 1.0f : 0.0f;
      float ax = fabsf(x);
      float e = __expf(-ax);
      float bce = fmaxf(x, 0.0f) - x * t + __logf(1.0f + e);
      vc += bce * w;
    }
  }
  int posb = valid ? g_pos[idx] : 0;
  if (posb) {
    int mg = g_mg[idx];
    float4 A = g_anc[LOFF + q];
    float aw = A.z - A.x, ah = A.w - A.y;
    float acx = A.x + 0.5f * aw, acy = A.y + 0.5f * ah;
    float4 gb = tb4[b * NG + mg];
    float gw = gb.z - gb.x, gh = gb.w - gb.y;
    float gcx = gb.x + 0.5f * gw, gcy = gb.y + 0.5f * gh;
    const float* rbase = reg + (b * 36 + a * 4) * HW + pix;
    vb += fabsf(rbase[0] - (gcx - acx) / aw);
    vb += fabsf(rbase[HW] - (gcy - acy) / ah);
    vb += fabsf(rbase[2 * HW] - logf(gw / aw));
    vb += fabsf(rbase[3 * HW] - logf(gh / ah));
  }
}

__global__ __launch_bounds__(256) void k_loss(
    const float* __restrict__ c0, const float* __restrict__ c1,
    const float* __restrict__ c2, const float* __restrict__ c3,
    const float* __restrict__ c4, const float* __restrict__ r0,
    const float* __restrict__ r1, const float* __restrict__ r2,
    const float* __restrict__ r3, const float* __restrict__ r4,
    const float* __restrict__ tb) {
  const float4* tb4 = reinterpret_cast<const float4*>(tb);
  int T = blockIdx.x * 256 + threadIdx.x;
  bool valid = T < BK;
  int Tc = valid ? T : 0;
  float vc = 0.0f, vb = 0.0f;
  if (Tc < 720000)       level_term<10000, 90000, 0, 0>(c0, r0, tb4, Tc, valid, vc, vb);
  else if (Tc < 900000)  level_term<2500, 22500, 720000, 90000>(c1, r1, tb4, Tc - 720000, valid, vc, vb);
  else if (Tc < 945000)  level_term<625, 5625, 900000, 112500>(c2, r2, tb4, Tc - 900000, valid, vc, vb);
  else if (Tc < 957168)  level_term<169, 1521, 945000, 118125>(c3, r3, tb4, Tc - 945000, valid, vc, vb);
  else                   level_term<49, 441, 957168, 119646>(c4, r4, tb4, Tc - 957168, valid, vc, vb);

#pragma unroll
  for (int off = 32; off; off >>= 1) {
    vc += __shfl_down(vc, off);
    vb += __shfl_down(vb, off);
  }
  __shared__ float sc_[4], sb_[4];
  int lane = threadIdx.x & 63;
  int wid = threadIdx.x >> 6;
  if (lane == 0) { sc_[wid] = vc; sb_[wid] = vb; }
  __syncthreads();
  if (threadIdx.x == 0) {
    float tc = sc_[0] + sc_[1] + sc_[2] + sc_[3];
    float tbx = sb_[0] + sb_[1] + sb_[2] + sb_[3];
    int slot = blockIdx.x & 255;
    if (tc != 0.0f) atomicAdd(&g_accs[slot][0], (double)tc);
    if (tbx != 0.0f) atomicAdd(&g_accs[slot][1], (double)tbx);
  }
}

// ---------------- kernel 4: finalize ----------------
__global__ __launch_bounds__(256) void k_fin(float* __restrict__ out) {
  int t = threadIdx.x;
  double a0 = g_accs[t][0];
  double a1 = g_accs[t][1];
#pragma unroll
  for (int off = 32; off; off >>= 1) {
    a0 += __shfl_down(a0, off);
    a1 += __shfl_down(a1, off);
  }
  __shared__ double s0[4], s1[4];
  if ((t & 63) == 0) { s0[t >> 6] = a0; s1[t >> 6] = a1; }
  __syncthreads();
  if (t == 0) {
    double A0 = s0[0] + s0[1] + s0[2] + s0[3];
    double A1 = s1[0] + s1[1] + s1[2] + s1[3];
    double n = (double)g_ns;
    out[0] = (float)(A0 / n);
    out[1] = (float)(A1 / n);
  }
}

// ---------------- launcher ----------------
extern "C" void kernel_launch(void* const* d_in, const int* in_sizes, int n_in,
                              void* d_out, int out_size, void* d_ws, size_t ws_size,
                              hipStream_t stream) {
  // setup_inputs() inserts cls/reg INTERLEAVED: cls0,reg0,cls1,reg1,...,tb,tcls
  const float* c0 = (const float*)d_in[0];
  const float* r0 = (const float*)d_in[1];
  const float* c1 = (const float*)d_in[2];
  const float* r1 = (const float*)d_in[3];
  const float* c2 = (const float*)d_in[4];
  const float* r2 = (const float*)d_in[5];
  const float* c3 = (const float*)d_in[6];
  const float* r3 = (const float*)d_in[7];
  const float* c4 = (const float*)d_in[8];
  const float* r4 = (const float*)d_in[9];
  const float* tb = (const float*)d_in[10];
  const int* tcls = (const int*)d_in[11];
  float* out = (float*)d_out;

  k_setup<<<dim3((KTOT + 255) / 256), dim3(256), 0, stream>>>();
  k_gtmax2<<<dim3(NB * NG), dim3(256), 0, stream>>>(tb);
  k_assign<<<dim3((KTOT + 256 * APB - 1) / (256 * APB), NB), dim3(256), 0, stream>>>(tb, tcls);
  k_loss<<<dim3((BK + 255) / 256), dim3(256), 0, stream>>>(c0, c1, c2, c3, c4, r0, r1, r2,
                                                           r3, r4, tb);
  k_fin<<<dim3(1), dim3(256), 0, stream>>>(out);
}

// Round 6
// 157.306 us; speedup vs baseline: 4.9273x; 1.0563x over previous
//
#include <hip/hip_runtime.h>
#include <cstdint>

#define DEVINL __device__ __forceinline__

// ---------------- problem geometry ----------------
constexpr int NB = 8;        // batch
constexpr int NG = 50;       // gts per image
constexpr int KTOT = 120087; // total anchors per image
constexpr int BK = NB * KTOT;

constexpr int L_W[5]   = {100, 50, 25, 13, 7};
constexpr int L_K[5]   = {90000, 22500, 5625, 1521, 441};
constexpr int L_OFF[5] = {0, 90000, 112500, 118125, 119646};
constexpr int L_STR[5] = {8, 16, 32, 64, 128};
constexpr int L_WSB[5] = {0, 720000, 900000, 945000, 957168}; // L_OFF * NB

// base anchor tables (float64, matching numpy bit-for-bit)
constexpr double HR_T[3] = {0.7071067811865476, 1.0, 1.4142135623730951}; // sqrt(ratios)
constexpr double WR_T[3] = {1.0 / HR_T[0], 1.0, 1.0 / HR_T[2]};          // 1/sqrt(ratios)
constexpr double SC_T[3] = {4.0, 5.039684199579493, 6.3496042078727974}; // 4*2^(i/3)

// ---------------- device-global scratch ----------------
__device__ float4 g_anc[KTOT];        // precomputed f32 anchors (shared by ALL passes)
__device__ double g_accs[256][2];     // hashed loss accumulators
__device__ unsigned g_ns;
__device__ unsigned g_gtmax[NB * NG];
__device__ int8_t g_lab[BK];
__device__ __align__(8) int8_t g_lw[BK];
__device__ int8_t g_pos[BK];
__device__ int8_t g_mg[BK];

// ---------------- helpers ----------------
// monotonic float -> unsigned mapping (order- and equality-preserving)
DEVINL unsigned encf(float f) {
  unsigned u = __float_as_uint(f);
  return (u & 0x80000000u) ? ~u : (u | 0x80000000u);
}
// enc(+0.0f)=0x80000000; iou>0 <=> enc(iou)>0x80000000u

DEVINL int lvl_of(int k) {
  return (k < 90000) ? 0 : (k < 112500) ? 1 : (k < 118125) ? 2 : (k < 119646) ? 3 : 4;
}

// the ONLY IoU expression — identical instruction sequence everywhere
DEVINL float iou_one(float ax0, float ay0, float ax1, float ay1, float areaA,
                     float bx0, float by0, float bx1, float by1, float areaB) {
  float ltx = fmaxf(ax0, bx0);
  float lty = fmaxf(ay0, by0);
  float rbx = fminf(ax1, bx1);
  float rby = fminf(ay1, by1);
  float wx = fmaxf(rbx - ltx, 0.0f);
  float wy = fmaxf(rby - lty, 0.0f);
  float inter = wx * wy;
  return __fdividef(inter, areaA + areaB - inter);
}

// ---------------- kernel 0: setup (init scalars + precompute anchors) -------
__global__ __launch_bounds__(256) void k_setup() {
  if (blockIdx.x == 0) {
    int t = threadIdx.x;
    g_accs[t][0] = 0.0;
    g_accs[t][1] = 0.0;
    if (t == 0) g_ns = 0u;
  }
  int k = blockIdx.x * 256 + threadIdx.x;
  if (k >= KTOT) return;
  int l = lvl_of(k);
  int r = k - L_OFF[l];
  int loc = r / 9;
  int a = r - loc * 9;
  int W = L_W[l];
  int y = loc / W;
  int x = loc - y * W;
  int st = L_STR[l];
  int ridx = a / 3;
  int sidx = a - ridx * 3;
  double wsz = WR_T[ridx] * SC_T[sidx] * (double)st;
  double hsz = HR_T[ridx] * SC_T[sidx] * (double)st;
  double cx = (double)(x * st);
  double cy = (double)(y * st);
  g_anc[k] = make_float4((float)(cx - wsz * 0.5), (float)(cy - hsz * 0.5),
                         (float)(cx + wsz * 0.5), (float)(cy + hsz * 0.5));
}

// ---------------- kernel 1: analytic per-(b,g) gt_max ----------------------
// 1D overlap ox(c) is concave piecewise-linear in the anchor center, IoU is
// monotone in the separable intersection I=ox*oy, and the inside-validity
// region is an axis-aligned box. So the constrained grid argmax per shape is
// among {floor/ceil of box center (+/-1 slop)} ∪ {validity bounds} ∪ {grid
// bounds} per axis. All candidates are evaluated with the REAL g_anc values
// and the REAL iou_one, so the max is bit-identical to brute-force.
DEVINL int axis_cand(int xi, int i0, int lo, int hi, int Wm1) {
  int c;
  if (xi < 4) c = i0 - 1 + xi;
  else if (xi == 4) c = lo;
  else if (xi == 5) c = lo + 1;
  else if (xi == 6) c = hi - 1;
  else if (xi == 7) c = hi;
  else if (xi == 8) c = 0;
  else c = Wm1;
  return min(max(c, 0), Wm1);
}

__global__ __launch_bounds__(256) void k_gtmax2(const float* __restrict__ tb) {
  const int bg = blockIdx.x; // b*NG + g
  float4 v = reinterpret_cast<const float4*>(tb)[bg];
  const float bx0 = v.x, by0 = v.y, bx1 = v.z, by1 = v.w;
  const float areaB = (bx1 - bx0) * (by1 - by0);
  const float bcx = 0.5f * (bx0 + bx1), bcy = 0.5f * (by0 + by1);

  float m = -1.0f;
  for (int t = threadIdx.x; t < 4500; t += 256) {
    int l = t / 900;
    int rem = t - l * 900;
    int a = rem / 100;
    int rem2 = rem - a * 100;
    int xi = rem2 / 10;
    int yi = rem2 - xi * 10;
    int W = (l == 0) ? 100 : (l == 1) ? 50 : (l == 2) ? 25 : (l == 3) ? 13 : 7;
    int loff = (l == 0) ? 0 : (l == 1) ? 90000 : (l == 2) ? 112500
               : (l == 3) ? 118125 : 119646;
    float stf = (float)(8 << l);
    float4 A0 = g_anc[loff + a]; // anchor at grid (0,0): A0.x = -w/2, A0.y = -h/2
    float whalf = -A0.x;
    float hhalf = -A0.y;
    int i0x = (int)floorf(bcx / stf);
    int lox = (int)ceilf(whalf / stf);
    int hix = (int)floorf((800.0f - whalf) / stf);
    int i0y = (int)floorf(bcy / stf);
    int loy = (int)ceilf(hhalf / stf);
    int hiy = (int)floorf((800.0f - hhalf) / stf);
    int cx = axis_cand(xi, i0x, lox, hix, W - 1);
    int cy = axis_cand(yi, i0y, loy, hiy, W - 1);
    int k = loff + (cy * W + cx) * 9 + a;
    float4 A = g_anc[k];
    bool inside = (A.x >= 0.0f) & (A.y >= 0.0f) & (A.z <= 800.0f) & (A.w <= 800.0f);
    float areaA = (A.z - A.x) * (A.w - A.y);
    float iou = inside ? iou_one(A.x, A.y, A.z, A.w, areaA,
                                 bx0, by0, bx1, by1, areaB)
                       : -1.0f;
    m = fmaxf(m, iou);
  }
#pragma unroll
  for (int off = 32; off; off >>= 1) m = fmaxf(m, __shfl_down(m, off));
  __shared__ float s_m[4];
  int lane = threadIdx.x & 63, wid = threadIdx.x >> 6;
  if (lane == 0) s_m[wid] = m;
  __syncthreads();
  if (threadIdx.x == 0) {
    float r = fmaxf(fmaxf(s_m[0], s_m[1]), fmaxf(s_m[2], s_m[3]));
    g_gtmax[bg] = encf(r); // sole writer, no atomic
  }
}

// ---------------- kernel 2: assignment with wave-extent gt pruning ---------
// Each thread: APB consecutive anchors -> wave covers 256 consecutive anchors
// (~28 grid locs). Per-wave bbox over its INSIDE anchors gives a sound skip:
// if either axis has min(wmax1,g1)-max(wmin0,g0) <= 0, every anchor's IoU
// with that gt is exactly 0 => no observable contribution (best only matters
// >=0.4; iou==qmax can't fire, qmax>0; arg only consumed when pos).
// Outside/invalid anchors use a sentinel far box (IoU==0 naturally), removing
// the per-pair 'inside' select, and are excluded from the extent.
constexpr int APB = 4;
__global__ __launch_bounds__(256) void k_assign(const float* __restrict__ tb,
                                                const int* __restrict__ tcls) {
  const int b = blockIdx.y;
  __shared__ float s_b[NG][8]; // x0,y0,x1,y1,area,qmax
  __shared__ int s_cls[NG];
  __shared__ unsigned s_cnt;
  int tid = threadIdx.x;
  if (tid == 0) s_cnt = 0u;
  if (tid < NG) {
    float4 v = reinterpret_cast<const float4*>(tb)[b * NG + tid];
    s_b[tid][0] = v.x; s_b[tid][1] = v.y; s_b[tid][2] = v.z; s_b[tid][3] = v.w;
    s_b[tid][4] = (v.z - v.x) * (v.w - v.y);
    unsigned gm = g_gtmax[b * NG + tid];
    s_b[tid][5] = (gm > 0x80000000u) ? __uint_as_float(gm ^ 0x80000000u)
                                     : __uint_as_float(0x7FC00000u); // NaN: never ==
    s_cls[tid] = tcls[b * NG + tid];
  }
  __syncthreads();

  const int base = (blockIdx.x * 256 + tid) * APB;
  float Ax0[APB], Ay0[APB], Ax1[APB], Ay1[APB], areaA[APB];
  bool inside[APB];
  float ex0 = __builtin_inff(), ey0 = __builtin_inff();
  float ex1 = -__builtin_inff(), ey1 = -__builtin_inff();
#pragma unroll
  for (int ap = 0; ap < APB; ++ap) {
    int k = base + ap;
    bool valid = k < KTOT;
    float4 A = g_anc[valid ? k : 0];
    bool ins = valid & (A.x >= 0.0f) & (A.y >= 0.0f) & (A.z <= 800.0f) & (A.w <= 800.0f);
    inside[ap] = ins;
    ex0 = fminf(ex0, ins ? A.x : __builtin_inff());
    ey0 = fminf(ey0, ins ? A.y : __builtin_inff());
    ex1 = fmaxf(ex1, ins ? A.z : -__builtin_inff());
    ey1 = fmaxf(ey1, ins ? A.w : -__builtin_inff());
    if (!ins) A = make_float4(-4000.0f, -4000.0f, -3999.0f, -3999.0f);
    Ax0[ap] = A.x; Ay0[ap] = A.y; Ax1[ap] = A.z; Ay1[ap] = A.w;
    areaA[ap] = (A.z - A.x) * (A.w - A.y);
  }
  // wave butterfly: all lanes get the wave's inside-anchor extent
#pragma unroll
  for (int off = 1; off < 64; off <<= 1) {
    ex0 = fminf(ex0, __shfl_xor(ex0, off));
    ey0 = fminf(ey0, __shfl_xor(ey0, off));
    ex1 = fmaxf(ex1, __shfl_xor(ex1, off));
    ey1 = fmaxf(ey1, __shfl_xor(ey1, off));
  }

  float best[APB];
  int arg[APB], lqg[APB];
#pragma unroll
  for (int ap = 0; ap < APB; ++ap) { best[ap] = -2.0f; arg[ap] = 0; lqg[ap] = -1; }

  for (int g = 0; g < NG; ++g) {
    float gx0 = s_b[g][0], gy0 = s_b[g][1], gx1 = s_b[g][2], gy1 = s_b[g][3];
    float ox = fminf(ex1, gx1) - fmaxf(ex0, gx0);
    float oy = fminf(ey1, gy1) - fmaxf(ey0, gy0);
    if (ox > 0.0f && oy > 0.0f) { // wave-uniform -> s_cbranch skip
      float gar = s_b[g][4], qmx = s_b[g][5];
#pragma unroll
      for (int ap = 0; ap < APB; ++ap) {
        float iou = iou_one(Ax0[ap], Ay0[ap], Ax1[ap], Ay1[ap], areaA[ap],
                            gx0, gy0, gx1, gy1, gar);
        if (iou > best[ap]) { best[ap] = iou; arg[ap] = g; } // first max wins
        if (iou == qmx) lqg[ap] = g;                         // last g wins
      }
    }
  }

  int cnt = 0;
#pragma unroll
  for (int ap = 0; ap < APB; ++ap) {
    int k = base + ap;
    if (k < KTOT) {
      int lab = (best[ap] >= 0.5f) ? 1 : ((best[ap] >= 0.4f) ? -1 : 0);
      int mg = arg[ap];
      if (lqg[ap] >= 0) { lab = 1; mg = lqg[ap]; }
      bool pos = (lab == 1) && inside[ap];
      bool neg = (lab == 0) && inside[ap];
      int l = lvl_of(k);
      int r = k - L_OFF[l];
      int widx = L_WSB[l] + b * L_K[l] + r;
      g_lab[widx] = pos ? (int8_t)s_cls[mg] : (int8_t)0;
      g_lw[widx] = (pos || neg) ? 1 : 0;
      g_pos[widx] = pos ? 1 : 0;
      g_mg[widx] = (int8_t)mg;
      cnt += (pos || neg) ? 1 : 0;
    }
  }
#pragma unroll
  for (int off = 32; off; off >>= 1) cnt += __shfl_down(cnt, off);
  if ((tid & 63) == 0 && cnt) atomicAdd(&s_cnt, (unsigned)cnt);
  __syncthreads();
  if (tid == 0 && s_cnt) atomicAdd(&g_ns, s_cnt);
}

// ---------------- kernel 3: fused cls + bbox loss, thread-per-anchor-slot ----
template <int HW, int KL, int WSB, int LOFF>
DEVINL void level_term(const float* __restrict__ cls, const float* __restrict__ reg,
                       const float4* __restrict__ tb4, int j, bool valid,
                       float& vc, float& vb) {
  constexpr int NHW9 = 9 * HW;
  int b = j / NHW9;
  int r2 = j - b * NHW9;
  int a = r2 / HW;
  int pix = r2 - a * HW;
  int q = pix * 9 + a;
  int idx = WSB + b * KL + q;

  unsigned long long lwq =
      *reinterpret_cast<const unsigned long long*>(&g_lw[WSB + 8 * q]);
  int lab = g_lab[idx];
  const float* cbase = cls + (b * 72 + a * 8) * HW + pix;
  if (valid && lwq) {
#pragma unroll
    for (int c = 0; c < 8; ++c) {
      float w = (float)((unsigned)(lwq >> (8 * c)) & 0xffu);
      float x = cbase[c * HW];
      float t = (lab == c) ? 1.0f : 0.0f;
      float ax = fabsf(x);
      float e = __expf(-ax);
      float bce = fmaxf(x, 0.0f) - x * t + __logf(1.0f + e);
      vc += bce * w;
    }
  }
  int posb = valid ? g_pos[idx] : 0;
  if (posb) {
    int mg = g_mg[idx];
    float4 A = g_anc[LOFF + q];
    float aw = A.z - A.x, ah = A.w - A.y;
    float acx = A.x + 0.5f * aw, acy = A.y + 0.5f * ah;
    float4 gb = tb4[b * NG + mg];
    float gw = gb.z - gb.x, gh = gb.w - gb.y;
    float gcx = gb.x + 0.5f * gw, gcy = gb.y + 0.5f * gh;
    const float* rbase = reg + (b * 36 + a * 4) * HW + pix;
    vb += fabsf(rbase[0] - (gcx - acx) / aw);
    vb += fabsf(rbase[HW] - (gcy - acy) / ah);
    vb += fabsf(rbase[2 * HW] - logf(gw / aw));
    vb += fabsf(rbase[3 * HW] - logf(gh / ah));
  }
}

__global__ __launch_bounds__(256) void k_loss(
    const float* __restrict__ c0, const float* __restrict__ c1,
    const float* __restrict__ c2, const float* __restrict__ c3,
    const float* __restrict__ c4, const float* __restrict__ r0,
    const float* __restrict__ r1, const float* __restrict__ r2,
    const float* __restrict__ r3, const float* __restrict__ r4,
    const float* __restrict__ tb) {
  const float4* tb4 = reinterpret_cast<const float4*>(tb);
  int T = blockIdx.x * 256 + threadIdx.x;
  bool valid = T < BK;
  int Tc = valid ? T : 0;
  float vc = 0.0f, vb = 0.0f;
  if (Tc < 720000)       level_term<10000, 90000, 0, 0>(c0, r0, tb4, Tc, valid, vc, vb);
  else if (Tc < 900000)  level_term<2500, 22500, 720000, 90000>(c1, r1, tb4, Tc - 720000, valid, vc, vb);
  else if (Tc < 945000)  level_term<625, 5625, 900000, 112500>(c2, r2, tb4, Tc - 900000, valid, vc, vb);
  else if (Tc < 957168)  level_term<169, 1521, 945000, 118125>(c3, r3, tb4, Tc - 945000, valid, vc, vb);
  else                   level_term<49, 441, 957168, 119646>(c4, r4, tb4, Tc - 957168, valid, vc, vb);

#pragma unroll
  for (int off = 32; off; off >>= 1) {
    vc += __shfl_down(vc, off);
    vb += __shfl_down(vb, off);
  }
  __shared__ float sc_[4], sb_[4];
  int lane = threadIdx.x & 63;
  int wid = threadIdx.x >> 6;
  if (lane == 0) { sc_[wid] = vc; sb_[wid] = vb; }
  __syncthreads();
  if (threadIdx.x == 0) {
    float tc = sc_[0] + sc_[1] + sc_[2] + sc_[3];
    float tbx = sb_[0] + sb_[1] + sb_[2] + sb_[3];
    int slot = blockIdx.x & 255;
    if (tc != 0.0f) atomicAdd(&g_accs[slot][0], (double)tc);
    if (tbx != 0.0f) atomicAdd(&g_accs[slot][1], (double)tbx);
  }
}

// ---------------- kernel 4: finalize ----------------
__global__ __launch_bounds__(256) void k_fin(float* __restrict__ out) {
  int t = threadIdx.x;
  double a0 = g_accs[t][0];
  double a1 = g_accs[t][1];
#pragma unroll
  for (int off = 32; off; off >>= 1) {
    a0 += __shfl_down(a0, off);
    a1 += __shfl_down(a1, off);
  }
  __shared__ double s0[4], s1[4];
  if ((t & 63) == 0) { s0[t >> 6] = a0; s1[t >> 6] = a1; }
  __syncthreads();
  if (t == 0) {
    double A0 = s0[0] + s0[1] + s0[2] + s0[3];
    double A1 = s1[0] + s1[1] + s1[2] + s1[3];
    double n = (double)g_ns;
    out[0] = (float)(A0 / n);
    out[1] = (float)(A1 / n);
  }
}

// ---------------- launcher ----------------
extern "C" void kernel_launch(void* const* d_in, const int* in_sizes, int n_in,
                              void* d_out, int out_size, void* d_ws, size_t ws_size,
                              hipStream_t stream) {
  // setup_inputs() inserts cls/reg INTERLEAVED: cls0,reg0,cls1,reg1,...,tb,tcls
  const float* c0 = (const float*)d_in[0];
  const float* r0 = (const float*)d_in[1];
  const float* c1 = (const float*)d_in[2];
  const float* r1 = (const float*)d_in[3];
  const float* c2 = (const float*)d_in[4];
  const float* r2 = (const float*)d_in[5];
  const float* c3 = (const float*)d_in[6];
  const float* r3 = (const float*)d_in[7];
  const float* c4 = (const float*)d_in[8];
  const float* r4 = (const float*)d_in[9];
  const float* tb = (const float*)d_in[10];
  const int* tcls = (const int*)d_in[11];
  float* out = (float*)d_out;

  k_setup<<<dim3((KTOT + 255) / 256), dim3(256), 0, stream>>>();
  k_gtmax2<<<dim3(NB * NG), dim3(256), 0, stream>>>(tb);
  k_assign<<<dim3((KTOT + 256 * APB - 1) / (256 * APB), NB), dim3(256), 0, stream>>>(tb, tcls);
  k_loss<<<dim3((BK + 255) / 256), dim3(256), 0, stream>>>(c0, c1, c2, c3, c4, r0, r1, r2,
                                                           r3, r4, tb);
  k_fin<<<dim3(1), dim3(256), 0, stream>>>(out);
}